// Round 6
// baseline (1014.995 us; speedup 1.0000x reference)
//
#include <hip/hip_runtime.h>
#include <math.h>

#define DIM 64
#define BSH 8                  // bucket shift: 256 dst nodes per bucket
#define BSZ (1 << BSH)

__device__ __forceinline__ float leaky(float e) { return e > 0.f ? e : 0.2f * e; }

// ---------------- CSR build ----------------
__global__ void k_deg_init(int* deg, int n) {
    int i = blockIdx.x * blockDim.x + threadIdx.x;
    if (i < n) deg[i] = 1;  // self loop
}

__global__ void k_deg_count(const int* __restrict__ ei, int* deg, int E) {
    int i = blockIdx.x * blockDim.x + threadIdx.x;
    if (i < E) atomicAdd(&deg[ei[E + i]], 1);
}

__global__ void k_scan_block(const int* __restrict__ deg, int* excl, int* bsum, int n) {
    __shared__ int tmp[256];
    int i = blockIdx.x * 256 + threadIdx.x;
    int v = (i < n) ? deg[i] : 0;
    tmp[threadIdx.x] = v;
    __syncthreads();
    for (int off = 1; off < 256; off <<= 1) {
        int t = (threadIdx.x >= off) ? tmp[threadIdx.x - off] : 0;
        __syncthreads();
        tmp[threadIdx.x] += t;
        __syncthreads();
    }
    if (i < n) excl[i] = tmp[threadIdx.x] - v;   // exclusive within block
    if (threadIdx.x == 255) bsum[blockIdx.x] = tmp[255];
}

__global__ void k_scan_partials(int* bsum, int nb) {   // nb <= 512
    __shared__ int tmp[512];
    int t = threadIdx.x;
    int v = (t < nb) ? bsum[t] : 0;
    tmp[t] = v;
    __syncthreads();
    for (int off = 1; off < 512; off <<= 1) {
        int u = (t >= off) ? tmp[t - off] : 0;
        __syncthreads();
        tmp[t] += u;
        __syncthreads();
    }
    if (t < nb) bsum[t] = tmp[t] - v;  // exclusive block offsets
}

__global__ void k_scan_finish(int* excl, const int* __restrict__ bsum, int n, int total) {
    int i = blockIdx.x * blockDim.x + threadIdx.x;
    if (i < n) excl[i] += bsum[i >> 8];
    if (i == 0) excl[n] = total;
}

// bucket cursors: boff[b] = row_ptr[b*BSZ] - b*BSZ (self-loop slots excluded
// from the edge-partition region)
__global__ void k_bucket_init(const int* __restrict__ row_ptr, int* bcur, int NB) {
    int b = blockIdx.x * blockDim.x + threadIdx.x;
    if (b < NB) bcur[b] = row_ptr[b << BSH] - (b << BSH);
}

// phase C: partition edges into per-bucket dense regions (packed 8B writes)
__global__ void k_partition(const int* __restrict__ ei, int* bcur, int2* __restrict__ part,
                            int E) {
    int i = blockIdx.x * blockDim.x + threadIdx.x;
    if (i >= E) return;
    int s = ei[i];
    int d = ei[E + i];
    int p = atomicAdd(&bcur[d >> BSH], 1);
    part[p] = make_int2(s, d);
}

// phase D: one block per bucket; LDS cursors; csr writes land in a ~16KB
// cache-resident window -> dense line fills, no HBM write amplification.
__global__ __launch_bounds__(256) void k_bucket_scatter(
        const int* __restrict__ row_ptr, const int2* __restrict__ part,
        int* __restrict__ csr, int n) {
    __shared__ int lcur[BSZ];
    int b = blockIdx.x;
    int d0 = b << BSH;
    int nb = min(BSZ, n - d0);
    // self loops (slot 0 of each node) + cursor init
    for (int j = threadIdx.x; j < nb; j += 256) {
        int node = d0 + j;
        int slot = row_ptr[node];
        csr[slot] = node;
        lcur[j] = slot + 1;
    }
    __syncthreads();
    int pbeg = row_ptr[d0] - d0;
    int dend = d0 + nb;
    int pend = row_ptr[dend] - dend;
    for (int p = pbeg + (int)threadIdx.x; p < pend; p += 256) {
        int2 e = part[p];
        int slot = atomicAdd(&lcur[e.y - d0], 1);
        csr[slot] = e.x;
    }
}

// ---------------- per-layer: K-tiled LDS GEMM + attention projections ----------------
template <int FIN>
__global__ __launch_bounds__(256, 4) void k_gemm_al(
        const float* __restrict__ x, int do_relu,
        const float* __restrict__ W,
        const float* __restrict__ as_, const float* __restrict__ ad_,
        float* __restrict__ h, float* __restrict__ als, float* __restrict__ ald,
        int n) {
    constexpr int KT = 64;
    constexpr int BM = 64;
    __shared__ float ws[KT * 64];        // [k][col]
    __shared__ float xs[BM * (KT + 1)];  // [row][k], stride 65

    const int tid = threadIdx.x;
    const int row0 = blockIdx.x * BM;
    const int rt = tid >> 4, ct = tid & 15;
    const int r0 = rt * 4, c0 = ct * 4;

    float acc[4][4];
#pragma unroll
    for (int i = 0; i < 4; ++i)
#pragma unroll
        for (int j = 0; j < 4; ++j) acc[i][j] = 0.f;

    for (int kt = 0; kt < FIN; kt += KT) {
#pragma unroll
        for (int p = 0; p < KT * 16 / 256; ++p) {
            int i = tid + p * 256;
            *reinterpret_cast<float4*>(&ws[i * 4]) =
                *reinterpret_cast<const float4*>(&W[kt * 64 + i * 4]);
        }
#pragma unroll
        for (int p = 0; p < BM * (KT / 4) / 256; ++p) {
            int i = tid + p * 256;
            int r = i >> 4;          // 16 quads per row
            int kq = i & 15;
            int grow = row0 + r;
            float4 v = make_float4(0.f, 0.f, 0.f, 0.f);
            if (grow < n)
                v = *reinterpret_cast<const float4*>(&x[(size_t)grow * FIN + kt + kq * 4]);
            if (do_relu) {
                v.x = fmaxf(v.x, 0.f); v.y = fmaxf(v.y, 0.f);
                v.z = fmaxf(v.z, 0.f); v.w = fmaxf(v.w, 0.f);
            }
            float* dst = &xs[r * (KT + 1) + kq * 4];
            dst[0] = v.x; dst[1] = v.y; dst[2] = v.z; dst[3] = v.w;
        }
        __syncthreads();

#pragma unroll 4
        for (int k = 0; k < KT; ++k) {
            float4 wv = *reinterpret_cast<const float4*>(&ws[k * 64 + c0]);
            float xv0 = xs[(r0 + 0) * (KT + 1) + k];
            float xv1 = xs[(r0 + 1) * (KT + 1) + k];
            float xv2 = xs[(r0 + 2) * (KT + 1) + k];
            float xv3 = xs[(r0 + 3) * (KT + 1) + k];
            acc[0][0] = fmaf(xv0, wv.x, acc[0][0]);
            acc[0][1] = fmaf(xv0, wv.y, acc[0][1]);
            acc[0][2] = fmaf(xv0, wv.z, acc[0][2]);
            acc[0][3] = fmaf(xv0, wv.w, acc[0][3]);
            acc[1][0] = fmaf(xv1, wv.x, acc[1][0]);
            acc[1][1] = fmaf(xv1, wv.y, acc[1][1]);
            acc[1][2] = fmaf(xv1, wv.z, acc[1][2]);
            acc[1][3] = fmaf(xv1, wv.w, acc[1][3]);
            acc[2][0] = fmaf(xv2, wv.x, acc[2][0]);
            acc[2][1] = fmaf(xv2, wv.y, acc[2][1]);
            acc[2][2] = fmaf(xv2, wv.z, acc[2][2]);
            acc[2][3] = fmaf(xv2, wv.w, acc[2][3]);
            acc[3][0] = fmaf(xv3, wv.x, acc[3][0]);
            acc[3][1] = fmaf(xv3, wv.y, acc[3][1]);
            acc[3][2] = fmaf(xv3, wv.z, acc[3][2]);
            acc[3][3] = fmaf(xv3, wv.w, acc[3][3]);
        }
        __syncthreads();
    }

    float4 asv = *reinterpret_cast<const float4*>(&as_[c0]);
    float4 adv = *reinterpret_cast<const float4*>(&ad_[c0]);
#pragma unroll
    for (int i = 0; i < 4; ++i) {
        int grow = row0 + r0 + i;
        if (grow < n) {
            *reinterpret_cast<float4*>(&h[(size_t)grow * 64 + c0]) =
                make_float4(acc[i][0], acc[i][1], acc[i][2], acc[i][3]);
        }
        float ps = acc[i][0] * asv.x + acc[i][1] * asv.y +
                   acc[i][2] * asv.z + acc[i][3] * asv.w;
        float pd = acc[i][0] * adv.x + acc[i][1] * adv.y +
                   acc[i][2] * adv.z + acc[i][3] * adv.w;
#pragma unroll
        for (int off = 1; off < 16; off <<= 1) {
            ps += __shfl_xor(ps, off);
            pd += __shfl_xor(pd, off);
        }
        if (ct == 0 && grow < n) { als[grow] = ps; ald[grow] = pd; }
    }
}

// ---------------- per-layer: node-parallel logits + exact max ----------------
// thread per node: ald[d] is a scalar, max local, att writes sequential.
__global__ void k_logits_max(const int* __restrict__ row_ptr, const int* __restrict__ csr,
                             const float* __restrict__ als, const float* __restrict__ ald,
                             float* __restrict__ att, float* __restrict__ mmax, int n) {
    int i = blockIdx.x * blockDim.x + threadIdx.x;
    if (i >= n) return;
    int beg = row_ptr[i], end = row_ptr[i + 1];
    float adv = ald[i];
    float m = -INFINITY;
    for (int p = beg; p < end; ++p) {
        float e = leaky(als[csr[p]] + adv);
        att[p] = e;
        m = fmaxf(m, e);
    }
    mmax[i] = m;
}

// ---------------- per-layer: branch-free gather aggregation ----------------
// wave per destination node; lane = feature dim; 4 independent h-gathers in flight.
__global__ void k_node_aggr(const int* __restrict__ row_ptr, const int* __restrict__ csr,
                            const float* __restrict__ att, const float* __restrict__ mmax,
                            const float* __restrict__ h, const float* __restrict__ bias,
                            float* __restrict__ out, int n) {
    int wid = threadIdx.x >> 6, lane = threadIdx.x & 63;
    int node = blockIdx.x * (blockDim.x >> 6) + wid;
    if (node >= n) return;
    int beg = row_ptr[node], end = row_ptr[node + 1];
    float m = mmax[node];
    float ssum = 0.f, acc = 0.f;
    int p = beg;
    for (; p + 4 <= end; p += 4) {
        int s0 = csr[p], s1 = csr[p + 1], s2 = csr[p + 2], s3 = csr[p + 3];
        float e0 = att[p], e1 = att[p + 1], e2 = att[p + 2], e3 = att[p + 3];
        float h0 = h[(size_t)s0 * DIM + lane];
        float h1 = h[(size_t)s1 * DIM + lane];
        float h2 = h[(size_t)s2 * DIM + lane];
        float h3 = h[(size_t)s3 * DIM + lane];
        float w0 = __expf(e0 - m), w1 = __expf(e1 - m);
        float w2 = __expf(e2 - m), w3 = __expf(e3 - m);
        ssum += (w0 + w1) + (w2 + w3);
        acc = fmaf(w0, h0, acc);
        acc = fmaf(w1, h1, acc);
        acc = fmaf(w2, h2, acc);
        acc = fmaf(w3, h3, acc);
    }
    for (; p < end; ++p) {
        int s = csr[p];
        float e = att[p];
        float hv = h[(size_t)s * DIM + lane];
        float w = __expf(e - m);
        ssum += w;
        acc = fmaf(w, hv, acc);
    }
    out[(size_t)node * DIM + lane] = acc / ssum + bias[lane];
}

extern "C" void kernel_launch(void* const* d_in, const int* in_sizes, int n_in,
                              void* d_out, int out_size, void* d_ws, size_t ws_size,
                              hipStream_t stream) {
    const float* x = (const float*)d_in[0];
    const int* ei = (const int*)d_in[1];   // harness converts integer inputs to int32
    const int n = out_size / DIM;          // 100000
    const int E = in_sizes[1] / 2;         // 1600000
    const int total_edges = E + n;
    const int NB = (n + BSZ - 1) >> BSH;   // 391 buckets

    const float *W[3], *as_[3], *ad_[3], *b[3];
    for (int l = 0; l < 3; ++l) {
        W[l]  = (const float*)d_in[2 + 4 * l];
        as_[l] = (const float*)d_in[3 + 4 * l];
        ad_[l] = (const float*)d_in[4 + 4 * l];
        b[l]  = (const float*)d_in[5 + 4 * l];
    }

    // workspace carve (256B aligned). Inter-layer activations live in d_out.
    // part (CSR-build only) overlays att (layers only) - disjoint lifetimes.
    char* ws = (char*)d_ws;
    size_t off = 0;
    auto alloc = [&](size_t bytes) {
        void* p = ws + off;
        off = (off + bytes + 255) & ~(size_t)255;
        return p;
    };
    int* deg      = (int*)alloc((size_t)n * 4);
    int* row_ptr  = (int*)alloc((size_t)(n + 1) * 4);
    int* bsum     = (int*)alloc(512 * 4);
    int* bcur     = (int*)alloc((size_t)NB * 4);
    int* csr      = (int*)alloc((size_t)total_edges * 4);
    int2* part    = (int2*)alloc((size_t)E * 8);   // overlaid with att
    float* att    = (float*)part;
    float* mmax   = (float*)alloc((size_t)n * 4);
    float* h      = (float*)alloc((size_t)n * DIM * 4);
    float* als    = (float*)alloc((size_t)n * 4);
    float* ald    = (float*)alloc((size_t)n * 4);
    float* buf    = (float*)d_out;         // inter-layer activations

    const int nbn = (n + 255) / 256;       // 391 (<=512 for scan_partials)
    const int nbe = (E + 255) / 256;

    // ---- CSR build (once; shared by all 3 layers) ----
    k_deg_init<<<nbn, 256, 0, stream>>>(deg, n);
    k_deg_count<<<nbe, 256, 0, stream>>>(ei, deg, E);
    k_scan_block<<<nbn, 256, 0, stream>>>(deg, row_ptr, bsum, n);
    k_scan_partials<<<1, 512, 0, stream>>>(bsum, nbn);
    k_scan_finish<<<nbn, 256, 0, stream>>>(row_ptr, bsum, n, total_edges);
    k_bucket_init<<<(NB + 255) / 256, 256, 0, stream>>>(row_ptr, bcur, NB);
    k_partition<<<nbe, 256, 0, stream>>>(ei, bcur, part, E);
    k_bucket_scatter<<<NB, 256, 0, stream>>>(row_ptr, part, csr, n);

    // ---- 3 GAT layers ----
    const int aggr_blocks = (n + 3) / 4;   // 4 waves (nodes) per 256-thread block
    const int gemm_blocks = (n + 63) / 64;
    const float* xin = x;
    for (int l = 0; l < 3; ++l) {
        if (l == 0) {
            k_gemm_al<128><<<gemm_blocks, 256, 0, stream>>>(
                xin, 0, W[l], as_[l], ad_[l], h, als, ald, n);
        } else {
            k_gemm_al<64><<<gemm_blocks, 256, 0, stream>>>(
                xin, 1, W[l], as_[l], ad_[l], h, als, ald, n);
        }
        k_logits_max<<<nbn, 256, 0, stream>>>(row_ptr, csr, als, ald, att, mmax, n);
        float* dst = (l == 2) ? (float*)d_out : buf;
        k_node_aggr<<<aggr_blocks, 256, 0, stream>>>(row_ptr, csr, att, mmax, h, b[l], dst, n);
        xin = buf;
    }
}

// Round 7
// 548.772 us; speedup vs baseline: 1.8496x; 1.8496x over previous
//
#include <hip/hip_runtime.h>
#include <math.h>

#define DIM 64
#define BSH 3                  // bucket shift: 8 dst nodes per bucket (contention vs locality sweet spot)
#define BSZ (1 << BSH)

__device__ __forceinline__ float leaky(float e) { return e > 0.f ? e : 0.2f * e; }

// ---------------- CSR build ----------------
__global__ void k_deg_init(int* deg, int n) {
    int i = blockIdx.x * blockDim.x + threadIdx.x;
    if (i < n) deg[i] = 1;  // self loop
}

__global__ void k_deg_count(const int* __restrict__ ei, int* deg, int E) {
    int i = blockIdx.x * blockDim.x + threadIdx.x;
    if (i < E) atomicAdd(&deg[ei[E + i]], 1);
}

__global__ void k_scan_block(const int* __restrict__ deg, int* excl, int* bsum, int n) {
    __shared__ int tmp[256];
    int i = blockIdx.x * 256 + threadIdx.x;
    int v = (i < n) ? deg[i] : 0;
    tmp[threadIdx.x] = v;
    __syncthreads();
    for (int off = 1; off < 256; off <<= 1) {
        int t = (threadIdx.x >= off) ? tmp[threadIdx.x - off] : 0;
        __syncthreads();
        tmp[threadIdx.x] += t;
        __syncthreads();
    }
    if (i < n) excl[i] = tmp[threadIdx.x] - v;   // exclusive within block
    if (threadIdx.x == 255) bsum[blockIdx.x] = tmp[255];
}

__global__ void k_scan_partials(int* bsum, int nb) {   // nb <= 512
    __shared__ int tmp[512];
    int t = threadIdx.x;
    int v = (t < nb) ? bsum[t] : 0;
    tmp[t] = v;
    __syncthreads();
    for (int off = 1; off < 512; off <<= 1) {
        int u = (t >= off) ? tmp[t - off] : 0;
        __syncthreads();
        tmp[t] += u;
        __syncthreads();
    }
    if (t < nb) bsum[t] = tmp[t] - v;  // exclusive block offsets
}

__global__ void k_scan_finish(int* excl, const int* __restrict__ bsum, int n, int total) {
    int i = blockIdx.x * blockDim.x + threadIdx.x;
    if (i < n) excl[i] += bsum[i >> 8];
    if (i == 0) excl[n] = total;
}

// bucket cursors: boff[b] = row_ptr[b*BSZ] - b*BSZ (self-loop slots excluded
// from the edge-partition region)
__global__ void k_bucket_init(const int* __restrict__ row_ptr, int* bcur, int NB) {
    int b = blockIdx.x * blockDim.x + threadIdx.x;
    if (b < NB) bcur[b] = row_ptr[b << BSH] - (b << BSH);
}

// phase C: partition edges into per-bucket dense regions (packed 8B writes).
// 12500 bucket counters -> atomic chains ~128 deep (vs 4096 at 391 buckets,
// which measured 558us = pure same-address atomic serialization).
__global__ void k_partition(const int* __restrict__ ei, int* bcur, int2* __restrict__ part,
                            int E) {
    int i = blockIdx.x * blockDim.x + threadIdx.x;
    if (i >= E) return;
    int s = ei[i];
    int d = ei[E + i];
    int p = atomicAdd(&bcur[d >> BSH], 1);
    part[p] = make_int2(s, d);
}

// phase D: one block per bucket; LDS cursors; csr writes land in a ~1KB
// window -> dense line fills, no HBM write amplification.
__global__ __launch_bounds__(128) void k_bucket_scatter(
        const int* __restrict__ row_ptr, const int2* __restrict__ part,
        int* __restrict__ csr, int n) {
    __shared__ int lcur[BSZ];
    int b = blockIdx.x;
    int d0 = b << BSH;
    int nb = min(BSZ, n - d0);
    // self loops (slot 0 of each node) + cursor init
    for (int j = threadIdx.x; j < nb; j += 128) {
        int node = d0 + j;
        int slot = row_ptr[node];
        csr[slot] = node;
        lcur[j] = slot + 1;
    }
    __syncthreads();
    int pbeg = row_ptr[d0] - d0;
    int dend = d0 + nb;
    int pend = row_ptr[dend] - dend;
    for (int p = pbeg + (int)threadIdx.x; p < pend; p += 128) {
        int2 e = part[p];
        int slot = atomicAdd(&lcur[e.y - d0], 1);
        csr[slot] = e.x;
    }
}

// ---------------- per-layer: K-tiled LDS GEMM + attention projections ----------------
template <int FIN>
__global__ __launch_bounds__(256, 4) void k_gemm_al(
        const float* __restrict__ x, int do_relu,
        const float* __restrict__ W,
        const float* __restrict__ as_, const float* __restrict__ ad_,
        float* __restrict__ h, float* __restrict__ als, float* __restrict__ ald,
        int n) {
    constexpr int KT = 64;
    constexpr int BM = 64;
    __shared__ float ws[KT * 64];        // [k][col]
    __shared__ float xs[BM * (KT + 1)];  // [row][k], stride 65

    const int tid = threadIdx.x;
    const int row0 = blockIdx.x * BM;
    const int rt = tid >> 4, ct = tid & 15;
    const int r0 = rt * 4, c0 = ct * 4;

    float acc[4][4];
#pragma unroll
    for (int i = 0; i < 4; ++i)
#pragma unroll
        for (int j = 0; j < 4; ++j) acc[i][j] = 0.f;

    for (int kt = 0; kt < FIN; kt += KT) {
#pragma unroll
        for (int p = 0; p < KT * 16 / 256; ++p) {
            int i = tid + p * 256;
            *reinterpret_cast<float4*>(&ws[i * 4]) =
                *reinterpret_cast<const float4*>(&W[kt * 64 + i * 4]);
        }
#pragma unroll
        for (int p = 0; p < BM * (KT / 4) / 256; ++p) {
            int i = tid + p * 256;
            int r = i >> 4;          // 16 quads per row
            int kq = i & 15;
            int grow = row0 + r;
            float4 v = make_float4(0.f, 0.f, 0.f, 0.f);
            if (grow < n)
                v = *reinterpret_cast<const float4*>(&x[(size_t)grow * FIN + kt + kq * 4]);
            if (do_relu) {
                v.x = fmaxf(v.x, 0.f); v.y = fmaxf(v.y, 0.f);
                v.z = fmaxf(v.z, 0.f); v.w = fmaxf(v.w, 0.f);
            }
            float* dst = &xs[r * (KT + 1) + kq * 4];
            dst[0] = v.x; dst[1] = v.y; dst[2] = v.z; dst[3] = v.w;
        }
        __syncthreads();

#pragma unroll 4
        for (int k = 0; k < KT; ++k) {
            float4 wv = *reinterpret_cast<const float4*>(&ws[k * 64 + c0]);
            float xv0 = xs[(r0 + 0) * (KT + 1) + k];
            float xv1 = xs[(r0 + 1) * (KT + 1) + k];
            float xv2 = xs[(r0 + 2) * (KT + 1) + k];
            float xv3 = xs[(r0 + 3) * (KT + 1) + k];
            acc[0][0] = fmaf(xv0, wv.x, acc[0][0]);
            acc[0][1] = fmaf(xv0, wv.y, acc[0][1]);
            acc[0][2] = fmaf(xv0, wv.z, acc[0][2]);
            acc[0][3] = fmaf(xv0, wv.w, acc[0][3]);
            acc[1][0] = fmaf(xv1, wv.x, acc[1][0]);
            acc[1][1] = fmaf(xv1, wv.y, acc[1][1]);
            acc[1][2] = fmaf(xv1, wv.z, acc[1][2]);
            acc[1][3] = fmaf(xv1, wv.w, acc[1][3]);
            acc[2][0] = fmaf(xv2, wv.x, acc[2][0]);
            acc[2][1] = fmaf(xv2, wv.y, acc[2][1]);
            acc[2][2] = fmaf(xv2, wv.z, acc[2][2]);
            acc[2][3] = fmaf(xv2, wv.w, acc[2][3]);
            acc[3][0] = fmaf(xv3, wv.x, acc[3][0]);
            acc[3][1] = fmaf(xv3, wv.y, acc[3][1]);
            acc[3][2] = fmaf(xv3, wv.z, acc[3][2]);
            acc[3][3] = fmaf(xv3, wv.w, acc[3][3]);
        }
        __syncthreads();
    }

    float4 asv = *reinterpret_cast<const float4*>(&as_[c0]);
    float4 adv = *reinterpret_cast<const float4*>(&ad_[c0]);
#pragma unroll
    for (int i = 0; i < 4; ++i) {
        int grow = row0 + r0 + i;
        if (grow < n) {
            *reinterpret_cast<float4*>(&h[(size_t)grow * 64 + c0]) =
                make_float4(acc[i][0], acc[i][1], acc[i][2], acc[i][3]);
        }
        float ps = acc[i][0] * asv.x + acc[i][1] * asv.y +
                   acc[i][2] * asv.z + acc[i][3] * asv.w;
        float pd = acc[i][0] * adv.x + acc[i][1] * adv.y +
                   acc[i][2] * adv.z + acc[i][3] * adv.w;
#pragma unroll
        for (int off = 1; off < 16; off <<= 1) {
            ps += __shfl_xor(ps, off);
            pd += __shfl_xor(pd, off);
        }
        if (ct == 0 && grow < n) { als[grow] = ps; ald[grow] = pd; }
    }
}

// ---------------- per-layer: node-parallel logits + exact max ----------------
// thread per node: ald[d] is a scalar, max local, att writes sequential.
__global__ void k_logits_max(const int* __restrict__ row_ptr, const int* __restrict__ csr,
                             const float* __restrict__ als, const float* __restrict__ ald,
                             float* __restrict__ att, float* __restrict__ mmax, int n) {
    int i = blockIdx.x * blockDim.x + threadIdx.x;
    if (i >= n) return;
    int beg = row_ptr[i], end = row_ptr[i + 1];
    float adv = ald[i];
    float m = -INFINITY;
    for (int p = beg; p < end; ++p) {
        float e = leaky(als[csr[p]] + adv);
        att[p] = e;
        m = fmaxf(m, e);
    }
    mmax[i] = m;
}

// ---------------- per-layer: branch-free gather aggregation ----------------
// wave per destination node; lane = feature dim; 4 independent h-gathers in flight.
__global__ void k_node_aggr(const int* __restrict__ row_ptr, const int* __restrict__ csr,
                            const float* __restrict__ att, const float* __restrict__ mmax,
                            const float* __restrict__ h, const float* __restrict__ bias,
                            float* __restrict__ out, int n) {
    int wid = threadIdx.x >> 6, lane = threadIdx.x & 63;
    int node = blockIdx.x * (blockDim.x >> 6) + wid;
    if (node >= n) return;
    int beg = row_ptr[node], end = row_ptr[node + 1];
    float m = mmax[node];
    float ssum = 0.f, acc = 0.f;
    int p = beg;
    for (; p + 4 <= end; p += 4) {
        int s0 = csr[p], s1 = csr[p + 1], s2 = csr[p + 2], s3 = csr[p + 3];
        float e0 = att[p], e1 = att[p + 1], e2 = att[p + 2], e3 = att[p + 3];
        float h0 = h[(size_t)s0 * DIM + lane];
        float h1 = h[(size_t)s1 * DIM + lane];
        float h2 = h[(size_t)s2 * DIM + lane];
        float h3 = h[(size_t)s3 * DIM + lane];
        float w0 = __expf(e0 - m), w1 = __expf(e1 - m);
        float w2 = __expf(e2 - m), w3 = __expf(e3 - m);
        ssum += (w0 + w1) + (w2 + w3);
        acc = fmaf(w0, h0, acc);
        acc = fmaf(w1, h1, acc);
        acc = fmaf(w2, h2, acc);
        acc = fmaf(w3, h3, acc);
    }
    for (; p < end; ++p) {
        int s = csr[p];
        float e = att[p];
        float hv = h[(size_t)s * DIM + lane];
        float w = __expf(e - m);
        ssum += w;
        acc = fmaf(w, hv, acc);
    }
    out[(size_t)node * DIM + lane] = acc / ssum + bias[lane];
}

extern "C" void kernel_launch(void* const* d_in, const int* in_sizes, int n_in,
                              void* d_out, int out_size, void* d_ws, size_t ws_size,
                              hipStream_t stream) {
    const float* x = (const float*)d_in[0];
    const int* ei = (const int*)d_in[1];   // harness converts integer inputs to int32
    const int n = out_size / DIM;          // 100000
    const int E = in_sizes[1] / 2;         // 1600000
    const int total_edges = E + n;
    const int NB = (n + BSZ - 1) >> BSH;   // 12500 buckets

    const float *W[3], *as_[3], *ad_[3], *b[3];
    for (int l = 0; l < 3; ++l) {
        W[l]  = (const float*)d_in[2 + 4 * l];
        as_[l] = (const float*)d_in[3 + 4 * l];
        ad_[l] = (const float*)d_in[4 + 4 * l];
        b[l]  = (const float*)d_in[5 + 4 * l];
    }

    // workspace carve (256B aligned). Inter-layer activations live in d_out.
    // part (CSR-build only) overlays att (layers only) - disjoint lifetimes.
    char* ws = (char*)d_ws;
    size_t off = 0;
    auto alloc = [&](size_t bytes) {
        void* p = ws + off;
        off = (off + bytes + 255) & ~(size_t)255;
        return p;
    };
    int* deg      = (int*)alloc((size_t)n * 4);
    int* row_ptr  = (int*)alloc((size_t)(n + 1) * 4);
    int* bsum     = (int*)alloc(512 * 4);
    int* bcur     = (int*)alloc((size_t)NB * 4);
    int* csr      = (int*)alloc((size_t)total_edges * 4);
    int2* part    = (int2*)alloc((size_t)E * 8);   // overlaid with att
    float* att    = (float*)part;
    float* mmax   = (float*)alloc((size_t)n * 4);
    float* h      = (float*)alloc((size_t)n * DIM * 4);
    float* als    = (float*)alloc((size_t)n * 4);
    float* ald    = (float*)alloc((size_t)n * 4);
    float* buf    = (float*)d_out;         // inter-layer activations

    const int nbn = (n + 255) / 256;       // 391 (<=512 for scan_partials)
    const int nbe = (E + 255) / 256;

    // ---- CSR build (once; shared by all 3 layers) ----
    k_deg_init<<<nbn, 256, 0, stream>>>(deg, n);
    k_deg_count<<<nbe, 256, 0, stream>>>(ei, deg, E);
    k_scan_block<<<nbn, 256, 0, stream>>>(deg, row_ptr, bsum, n);
    k_scan_partials<<<1, 512, 0, stream>>>(bsum, nbn);
    k_scan_finish<<<nbn, 256, 0, stream>>>(row_ptr, bsum, n, total_edges);
    k_bucket_init<<<(NB + 255) / 256, 256, 0, stream>>>(row_ptr, bcur, NB);
    k_partition<<<nbe, 256, 0, stream>>>(ei, bcur, part, E);
    k_bucket_scatter<<<NB, 128, 0, stream>>>(row_ptr, part, csr, n);

    // ---- 3 GAT layers ----
    const int aggr_blocks = (n + 3) / 4;   // 4 waves (nodes) per 256-thread block
    const int gemm_blocks = (n + 63) / 64;
    const float* xin = x;
    for (int l = 0; l < 3; ++l) {
        if (l == 0) {
            k_gemm_al<128><<<gemm_blocks, 256, 0, stream>>>(
                xin, 0, W[l], as_[l], ad_[l], h, als, ald, n);
        } else {
            k_gemm_al<64><<<gemm_blocks, 256, 0, stream>>>(
                xin, 1, W[l], as_[l], ad_[l], h, als, ald, n);
        }
        k_logits_max<<<nbn, 256, 0, stream>>>(row_ptr, csr, als, ald, att, mmax, n);
        float* dst = (l == 2) ? (float*)d_out : buf;
        k_node_aggr<<<aggr_blocks, 256, 0, stream>>>(row_ptr, csr, att, mmax, h, b[l], dst, n);
        xin = buf;
    }
}

// Round 8
// 394.646 us; speedup vs baseline: 2.5719x; 1.3905x over previous
//
#include <hip/hip_runtime.h>
#include <math.h>

#define DIM 64
#define CBSH 9                 // coarse bucket: 512 dst nodes
#define CBSZ (1 << CBSH)
#define CHUNK 4096             // edges per partition block

__device__ __forceinline__ float leaky(float e) { return e > 0.f ? e : 0.2f * e; }

// ---------------- CSR build ----------------
__global__ void k_deg_init(int* deg, int n) {
    int i = blockIdx.x * blockDim.x + threadIdx.x;
    if (i < n) deg[i] = 1;  // self loop
}

// P1: per-block histogram over coarse buckets + merged global degree count.
__global__ __launch_bounds__(256) void k_part_hist(
        const int* __restrict__ ei, int* __restrict__ deg,
        int* __restrict__ hist2d, int E, int NPB, int NCB) {
    __shared__ int hist[256];
    int blk = blockIdx.x;
    int base = blk * CHUNK;
    int ecnt = min(CHUNK, E - base);
    for (int i = threadIdx.x; i < 256; i += 256) hist[i] = 0;
    __syncthreads();
    for (int i = threadIdx.x; i < ecnt; i += 256) {
        int d = ei[E + base + i];
        atomicAdd(&hist[d >> CBSH], 1);   // LDS
        atomicAdd(&deg[d], 1);            // global (replaces k_deg_count pass)
    }
    __syncthreads();
    for (int cb = threadIdx.x; cb < NCB; cb += 256)
        hist2d[cb * NPB + blk] = hist[cb];
}

__global__ void k_scan_block(const int* __restrict__ deg, int* excl, int* bsum, int n) {
    __shared__ int tmp[256];
    int i = blockIdx.x * 256 + threadIdx.x;
    int v = (i < n) ? deg[i] : 0;
    tmp[threadIdx.x] = v;
    __syncthreads();
    for (int off = 1; off < 256; off <<= 1) {
        int t = (threadIdx.x >= off) ? tmp[threadIdx.x - off] : 0;
        __syncthreads();
        tmp[threadIdx.x] += t;
        __syncthreads();
    }
    if (i < n) excl[i] = tmp[threadIdx.x] - v;   // exclusive within block
    if (threadIdx.x == 255) bsum[blockIdx.x] = tmp[255];
}

__global__ void k_scan_partials(int* bsum, int nb) {   // nb <= 512
    __shared__ int tmp[512];
    int t = threadIdx.x;
    int v = (t < nb) ? bsum[t] : 0;
    tmp[t] = v;
    __syncthreads();
    for (int off = 1; off < 512; off <<= 1) {
        int u = (t >= off) ? tmp[t - off] : 0;
        __syncthreads();
        tmp[t] += u;
        __syncthreads();
    }
    if (t < nb) bsum[t] = tmp[t] - v;  // exclusive block offsets
}

__global__ void k_scan_finish(int* excl, const int* __restrict__ bsum, int n, int total) {
    int i = blockIdx.x * blockDim.x + threadIdx.x;
    if (i < n) excl[i] += bsum[i >> 8];
    if (i == 0) excl[n] = total;
}

// P2: per coarse bucket, exclusive-scan the per-block counts -> run bases.
// Bucket's edge region base = row_ptr[d0] - d0 (self-loop slots excluded).
__global__ __launch_bounds__(512) void k_part_scan(
        const int* __restrict__ row_ptr, int* __restrict__ hist2d, int NPB) {
    __shared__ int tmp[512];
    int cb = blockIdx.x;
    int t = threadIdx.x;
    int v = (t < NPB) ? hist2d[cb * NPB + t] : 0;
    tmp[t] = v;
    __syncthreads();
    for (int off = 1; off < 512; off <<= 1) {
        int u = (t >= off) ? tmp[t - off] : 0;
        __syncthreads();
        tmp[t] += u;
        __syncthreads();
    }
    int d0 = cb << CBSH;
    int base = row_ptr[d0] - d0;
    if (t < NPB) hist2d[cb * NPB + t] = base + tmp[t] - v;
}

// P3: write edges into this block's private contiguous runs (one run per
// coarse bucket). All writes to a run come from one block -> one XCD ->
// full-line combining in L2 (round 7's 94MB cross-XCD bounce eliminated).
__global__ __launch_bounds__(256) void k_part_scatter(
        const int* __restrict__ ei, const int* __restrict__ hist2d,
        int2* __restrict__ part, int E, int NPB, int NCB) {
    __shared__ int gb[256];
    __shared__ int cnt[256];
    int blk = blockIdx.x;
    int base = blk * CHUNK;
    int ecnt = min(CHUNK, E - base);
    for (int i = threadIdx.x; i < NCB; i += 256) {
        gb[i] = hist2d[i * NPB + blk];
        cnt[i] = 0;
    }
    __syncthreads();
    for (int i = threadIdx.x; i < ecnt; i += 256) {
        int s = ei[base + i];
        int d = ei[E + base + i];
        int cb = d >> CBSH;
        int off = atomicAdd(&cnt[cb], 1);  // LDS ticket within run
        part[gb[cb] + off] = make_int2(s, d);
    }
}

// phase D: one block per coarse bucket; LDS cursors; csr writes land in a
// ~35KB L2-resident window -> dense line fills.
__global__ __launch_bounds__(256) void k_bucket_scatter(
        const int* __restrict__ row_ptr, const int2* __restrict__ part,
        int* __restrict__ csr, int n) {
    __shared__ int lcur[CBSZ];
    int d0 = blockIdx.x << CBSH;
    int nb = min(CBSZ, n - d0);
    for (int j = threadIdx.x; j < nb; j += 256) {
        int node = d0 + j;
        int slot = row_ptr[node];
        csr[slot] = node;     // self loop at slot 0
        lcur[j] = slot + 1;
    }
    __syncthreads();
    int pbeg = row_ptr[d0] - d0;
    int pend = row_ptr[d0 + nb] - (d0 + nb);
    for (int p = pbeg + (int)threadIdx.x; p < pend; p += 256) {
        int2 e = part[p];
        int slot = atomicAdd(&lcur[e.y - d0], 1);
        csr[slot] = e.x;
    }
}

// ---------------- per-layer: K-tiled LDS GEMM + attention projections ----------------
template <int FIN>
__global__ __launch_bounds__(256, 4) void k_gemm_al(
        const float* __restrict__ x, int do_relu,
        const float* __restrict__ W,
        const float* __restrict__ as_, const float* __restrict__ ad_,
        float* __restrict__ h, float* __restrict__ als, float* __restrict__ ald,
        int n) {
    constexpr int KT = 64;
    constexpr int BM = 64;
    __shared__ float ws[KT * 64];        // [k][col]
    __shared__ float xs[BM * (KT + 1)];  // [row][k], stride 65

    const int tid = threadIdx.x;
    const int row0 = blockIdx.x * BM;
    const int rt = tid >> 4, ct = tid & 15;
    const int r0 = rt * 4, c0 = ct * 4;

    float acc[4][4];
#pragma unroll
    for (int i = 0; i < 4; ++i)
#pragma unroll
        for (int j = 0; j < 4; ++j) acc[i][j] = 0.f;

    for (int kt = 0; kt < FIN; kt += KT) {
#pragma unroll
        for (int p = 0; p < KT * 16 / 256; ++p) {
            int i = tid + p * 256;
            *reinterpret_cast<float4*>(&ws[i * 4]) =
                *reinterpret_cast<const float4*>(&W[kt * 64 + i * 4]);
        }
#pragma unroll
        for (int p = 0; p < BM * (KT / 4) / 256; ++p) {
            int i = tid + p * 256;
            int r = i >> 4;          // 16 quads per row
            int kq = i & 15;
            int grow = row0 + r;
            float4 v = make_float4(0.f, 0.f, 0.f, 0.f);
            if (grow < n)
                v = *reinterpret_cast<const float4*>(&x[(size_t)grow * FIN + kt + kq * 4]);
            if (do_relu) {
                v.x = fmaxf(v.x, 0.f); v.y = fmaxf(v.y, 0.f);
                v.z = fmaxf(v.z, 0.f); v.w = fmaxf(v.w, 0.f);
            }
            float* dst = &xs[r * (KT + 1) + kq * 4];
            dst[0] = v.x; dst[1] = v.y; dst[2] = v.z; dst[3] = v.w;
        }
        __syncthreads();

#pragma unroll 4
        for (int k = 0; k < KT; ++k) {
            float4 wv = *reinterpret_cast<const float4*>(&ws[k * 64 + c0]);
            float xv0 = xs[(r0 + 0) * (KT + 1) + k];
            float xv1 = xs[(r0 + 1) * (KT + 1) + k];
            float xv2 = xs[(r0 + 2) * (KT + 1) + k];
            float xv3 = xs[(r0 + 3) * (KT + 1) + k];
            acc[0][0] = fmaf(xv0, wv.x, acc[0][0]);
            acc[0][1] = fmaf(xv0, wv.y, acc[0][1]);
            acc[0][2] = fmaf(xv0, wv.z, acc[0][2]);
            acc[0][3] = fmaf(xv0, wv.w, acc[0][3]);
            acc[1][0] = fmaf(xv1, wv.x, acc[1][0]);
            acc[1][1] = fmaf(xv1, wv.y, acc[1][1]);
            acc[1][2] = fmaf(xv1, wv.z, acc[1][2]);
            acc[1][3] = fmaf(xv1, wv.w, acc[1][3]);
            acc[2][0] = fmaf(xv2, wv.x, acc[2][0]);
            acc[2][1] = fmaf(xv2, wv.y, acc[2][1]);
            acc[2][2] = fmaf(xv2, wv.z, acc[2][2]);
            acc[2][3] = fmaf(xv2, wv.w, acc[2][3]);
            acc[3][0] = fmaf(xv3, wv.x, acc[3][0]);
            acc[3][1] = fmaf(xv3, wv.y, acc[3][1]);
            acc[3][2] = fmaf(xv3, wv.z, acc[3][2]);
            acc[3][3] = fmaf(xv3, wv.w, acc[3][3]);
        }
        __syncthreads();
    }

    float4 asv = *reinterpret_cast<const float4*>(&as_[c0]);
    float4 adv = *reinterpret_cast<const float4*>(&ad_[c0]);
#pragma unroll
    for (int i = 0; i < 4; ++i) {
        int grow = row0 + r0 + i;
        if (grow < n) {
            *reinterpret_cast<float4*>(&h[(size_t)grow * 64 + c0]) =
                make_float4(acc[i][0], acc[i][1], acc[i][2], acc[i][3]);
        }
        float ps = acc[i][0] * asv.x + acc[i][1] * asv.y +
                   acc[i][2] * asv.z + acc[i][3] * asv.w;
        float pd = acc[i][0] * adv.x + acc[i][1] * adv.y +
                   acc[i][2] * adv.z + acc[i][3] * adv.w;
#pragma unroll
        for (int off = 1; off < 16; off <<= 1) {
            ps += __shfl_xor(ps, off);
            pd += __shfl_xor(pd, off);
        }
        if (ct == 0 && grow < n) { als[grow] = ps; ald[grow] = pd; }
    }
}

// ---------------- per-layer: fused logits + exact softmax + aggregation ----------------
// wave per destination node. Per <=64-edge chunk: lanes compute logits in
// parallel (als gathers latency-parallel), shfl_xor max, then shfl-broadcast
// weights into a 4-deep-unrolled h-gather loop. deg>64: exact online rescale.
__global__ void k_node_aggr(const int* __restrict__ row_ptr, const int* __restrict__ csr,
                            const float* __restrict__ als, const float* __restrict__ ald,
                            const float* __restrict__ h, const float* __restrict__ bias,
                            float* __restrict__ out, int n) {
    int wid = threadIdx.x >> 6, lane = threadIdx.x & 63;
    int node = blockIdx.x * (blockDim.x >> 6) + wid;
    if (node >= n) return;
    int beg = row_ptr[node];
    int deg = row_ptr[node + 1] - beg;
    float adv = ald[node];
    float m = -INFINITY, ssum = 0.f, acc = 0.f;
    for (int c0 = 0; c0 < deg; c0 += 64) {
        int cn = min(64, deg - c0);
        int s_l = 0;
        float e_l = -INFINITY;
        if (lane < cn) {
            s_l = csr[beg + c0 + lane];
            e_l = leaky(als[s_l] + adv);
        }
        float cm = e_l;
#pragma unroll
        for (int off = 32; off; off >>= 1) cm = fmaxf(cm, __shfl_xor(cm, off));
        float mnew = fmaxf(m, cm);
        float sc = __expf(m - mnew);   // first chunk: exp(-inf)=0
        ssum *= sc; acc *= sc; m = mnew;
        int j = 0;
        for (; j + 4 <= cn; j += 4) {
            int s0 = __shfl(s_l, j),     s1 = __shfl(s_l, j + 1);
            int s2 = __shfl(s_l, j + 2), s3 = __shfl(s_l, j + 3);
            float f0 = __shfl(e_l, j),     f1 = __shfl(e_l, j + 1);
            float f2 = __shfl(e_l, j + 2), f3 = __shfl(e_l, j + 3);
            float h0 = h[(size_t)s0 * DIM + lane];
            float h1 = h[(size_t)s1 * DIM + lane];
            float h2 = h[(size_t)s2 * DIM + lane];
            float h3 = h[(size_t)s3 * DIM + lane];
            float w0 = __expf(f0 - m), w1 = __expf(f1 - m);
            float w2 = __expf(f2 - m), w3 = __expf(f3 - m);
            ssum += (w0 + w1) + (w2 + w3);
            acc = fmaf(w0, h0, acc);
            acc = fmaf(w1, h1, acc);
            acc = fmaf(w2, h2, acc);
            acc = fmaf(w3, h3, acc);
        }
        for (; j < cn; ++j) {
            int s = __shfl(s_l, j);
            float f = __shfl(e_l, j);
            float hv = h[(size_t)s * DIM + lane];
            float w = __expf(f - m);
            ssum += w;
            acc = fmaf(w, hv, acc);
        }
    }
    out[(size_t)node * DIM + lane] = acc / ssum + bias[lane];
}

extern "C" void kernel_launch(void* const* d_in, const int* in_sizes, int n_in,
                              void* d_out, int out_size, void* d_ws, size_t ws_size,
                              hipStream_t stream) {
    const float* x = (const float*)d_in[0];
    const int* ei = (const int*)d_in[1];   // harness converts integer inputs to int32
    const int n = out_size / DIM;          // 100000
    const int E = in_sizes[1] / 2;         // 1600000
    const int total_edges = E + n;
    const int NCB = (n + CBSZ - 1) >> CBSH;      // 196 coarse buckets (<=256)
    const int NPB = (E + CHUNK - 1) / CHUNK;     // 391 partition blocks (<=512)

    const float *W[3], *as_[3], *ad_[3], *b[3];
    for (int l = 0; l < 3; ++l) {
        W[l]  = (const float*)d_in[2 + 4 * l];
        as_[l] = (const float*)d_in[3 + 4 * l];
        ad_[l] = (const float*)d_in[4 + 4 * l];
        b[l]  = (const float*)d_in[5 + 4 * l];
    }

    // workspace carve (256B aligned). Inter-layer activations live in d_out.
    char* ws = (char*)d_ws;
    size_t off = 0;
    auto alloc = [&](size_t bytes) {
        void* p = ws + off;
        off = (off + bytes + 255) & ~(size_t)255;
        return p;
    };
    int* deg      = (int*)alloc((size_t)n * 4);
    int* row_ptr  = (int*)alloc((size_t)(n + 1) * 4);
    int* bsum     = (int*)alloc(512 * 4);
    int* hist2d   = (int*)alloc((size_t)NCB * NPB * 4);
    int* csr      = (int*)alloc((size_t)total_edges * 4);
    int2* part    = (int2*)alloc((size_t)E * 8);
    float* h      = (float*)alloc((size_t)n * DIM * 4);
    float* als    = (float*)alloc((size_t)n * 4);
    float* ald    = (float*)alloc((size_t)n * 4);
    float* buf    = (float*)d_out;         // inter-layer activations

    const int nbn = (n + 255) / 256;       // 391 (<=512 for scan_partials)

    // ---- CSR build (once; shared by all 3 layers) ----
    k_deg_init<<<nbn, 256, 0, stream>>>(deg, n);
    k_part_hist<<<NPB, 256, 0, stream>>>(ei, deg, hist2d, E, NPB, NCB);
    k_scan_block<<<nbn, 256, 0, stream>>>(deg, row_ptr, bsum, n);
    k_scan_partials<<<1, 512, 0, stream>>>(bsum, nbn);
    k_scan_finish<<<nbn, 256, 0, stream>>>(row_ptr, bsum, n, total_edges);
    k_part_scan<<<NCB, 512, 0, stream>>>(row_ptr, hist2d, NPB);
    k_part_scatter<<<NPB, 256, 0, stream>>>(ei, hist2d, part, E, NPB, NCB);
    k_bucket_scatter<<<NCB, 256, 0, stream>>>(row_ptr, part, csr, n);

    // ---- 3 GAT layers ----
    const int aggr_blocks = (n + 3) / 4;   // 4 waves (nodes) per 256-thread block
    const int gemm_blocks = (n + 63) / 64;
    const float* xin = x;
    for (int l = 0; l < 3; ++l) {
        if (l == 0) {
            k_gemm_al<128><<<gemm_blocks, 256, 0, stream>>>(
                xin, 0, W[l], as_[l], ad_[l], h, als, ald, n);
        } else {
            k_gemm_al<64><<<gemm_blocks, 256, 0, stream>>>(
                xin, 1, W[l], as_[l], ad_[l], h, als, ald, n);
        }
        float* dst = (l == 2) ? (float*)d_out : buf;
        k_node_aggr<<<aggr_blocks, 256, 0, stream>>>(row_ptr, csr, als, ald, h, b[l], dst, n);
        xin = buf;
    }
}